// Round 3
// baseline (868.522 us; speedup 1.0000x reference)
//
#include <hip/hip_runtime.h>
#include <hip/hip_bf16.h>

#define H 256
#define W 256
#define CIN 128
#define COUT 128
#define BATCH 8
#define LDA 136              // LDS row stride in bf16 elems (128 + 8 pad)
#define SLOT (66 * LDA)      // one 66-px halo row slot (8976 elems)

typedef float f32x4 __attribute__((ext_vector_type(4)));
typedef short bf16x8 __attribute__((ext_vector_type(8)));

static __device__ __forceinline__ unsigned short f2bf(float f) {
    unsigned int x = __float_as_uint(f);
    unsigned int r = (x + 0x7fffu + ((x >> 16) & 1u)) >> 16;
    return (unsigned short)r;
}

// Cross-kernel scratch (stream-ordered kernel launches provide visibility).
__device__ float g_s0[CIN];        // s[0][c] (un-normalized)
__device__ float g_bmax[BATCH];    // per-batch max |s[b][c]|
__device__ float g_partial[9 * COUT];  // per-kk partial sum of (w*scale)^2

// ---------------------------------------------------------------------------
// Prep stage 1: s = style @ w_mod + b_mod + 1. One block per batch image.
// ---------------------------------------------------------------------------
__global__ __launch_bounds__(256) void mod_style(
    const float* __restrict__ style, const float* __restrict__ w_mod,
    const float* __restrict__ b_mod)
{
    __shared__ float red[256];
    const int t = threadIdx.x;
    const int b = blockIdx.x;
    const int c = t & 127;
    const int half = t >> 7;

    float acc = 0.f;
    const float4* st4 = (const float4*)(style + b * 512 + half * 256);
    const float* wm = w_mod + half * 256 * CIN + c;
    for (int k4 = 0; k4 < 64; ++k4) {
        float4 s4 = st4[k4];
        const float* w = wm + k4 * 4 * CIN;
        acc += s4.x * w[0 * CIN];
        acc += s4.y * w[1 * CIN];
        acc += s4.z * w[2 * CIN];
        acc += s4.w * w[3 * CIN];
    }
    red[t] = acc;
    __syncthreads();
    if (t < 128) {
        float sval = red[t] + red[t + 128] + b_mod[t] + 1.0f;
        if (b == 0) g_s0[t] = sval;
        red[t] = fabsf(sval);
    }
    __syncthreads();
    for (int off = 64; off > 0; off >>= 1) {
        if (t < off) red[t] = fmaxf(red[t], red[t + off]);
        __syncthreads();
    }
    if (t == 0) g_bmax[b] = red[0];
}

// ---------------------------------------------------------------------------
// Prep stage 2: partial demod sums. One block per kk (9 blocks, 256 threads).
// ---------------------------------------------------------------------------
__global__ __launch_bounds__(256) void demod_partial(
    const float* __restrict__ kern)
{
    __shared__ float scale[CIN];
    __shared__ float red[256];
    const int t = threadIdx.x;
    const int kk = blockIdx.x;
    const int co = t & 127;
    const int half = t >> 7;

    if (t < 128) {
        float m = g_bmax[0];
        #pragma unroll
        for (int i = 1; i < BATCH; ++i) m = fmaxf(m, g_bmax[i]);
        const float he_std = 1.0f / sqrtf(1152.0f);
        scale[t] = g_s0[t] * (1.0f / m) * he_std;
    }
    __syncthreads();

    float ss = 0.f;
    const float* kbase = kern + (size_t)kk * 128 * 128 + co;
    for (int j = 0; j < 64; ++j) {
        int ci = half * 64 + j;
        float wv = kbase[(size_t)ci * 128] * scale[ci];
        ss += wv * wv;
    }
    red[t] = ss;
    __syncthreads();
    if (t < 128) g_partial[kk * 128 + t] = red[t] + red[t + 128];
}

// ---------------------------------------------------------------------------
// Prep stage 3: write pre-swizzled bf16 B-fragments (one unit per thread).
// Unit u = ((kk*4 + kc)*8 + ntile)*64 + lane; each unit 8 bf16 =
// B[k = kc*32 + (lane>>4)*8 + j][n = ntile*16 + (lane&15)], kk = kh*3+kw.
// ---------------------------------------------------------------------------
__global__ __launch_bounds__(256) void swizzle_kernel(
    const float* __restrict__ kern, unsigned short* __restrict__ wprep)
{
    __shared__ float scale[CIN];
    __shared__ float dArr[COUT];
    const int t = threadIdx.x;
    const int u = blockIdx.x * 256 + t;

    if (t < 128) {
        float m = g_bmax[0];
        #pragma unroll
        for (int i = 1; i < BATCH; ++i) m = fmaxf(m, g_bmax[i]);
        const float he_std = 1.0f / sqrtf(1152.0f);
        scale[t] = g_s0[t] * (1.0f / m) * he_std;
        float sum = 0.f;
        #pragma unroll
        for (int g = 0; g < 9; ++g) sum += g_partial[g * 128 + t];
        dArr[t] = rsqrtf(sum + 1e-8f);
    }
    __syncthreads();

    const int lane  = u & 63;
    const int ntile = (u >> 6) & 7;
    const int kc    = (u >> 9) & 3;
    const int kk    = u >> 11;
    const int co  = ntile * 16 + (lane & 15);
    const int cib = kc * 32 + (lane >> 4) * 8;
    const float dv = dArr[co];
    unsigned int packed[4];
    #pragma unroll
    for (int jp = 0; jp < 4; ++jp) {
        int ci0 = cib + jp * 2;
        float w0 = kern[(kk * 128 + ci0)     * 128 + co] * scale[ci0]     * dv;
        float w1 = kern[(kk * 128 + ci0 + 1) * 128 + co] * scale[ci0 + 1] * dv;
        packed[jp] = (unsigned int)f2bf(w0) | ((unsigned int)f2bf(w1) << 16);
    }
    ((uint4*)wprep)[u] = make_uint4(packed[0], packed[1], packed[2], packed[3]);
}

// ---------------------------------------------------------------------------
// 12 MFMA phases for one kh (one LDS row-slot). Carries the 1-phase-deep
// B-fragment register pipeline across calls (g = KH*12 + kw*4 + kc; the
// g==35 prefetch wraps to 0 for the next output row).
// ---------------------------------------------------------------------------
template<int KH>
static __device__ __forceinline__ void compute_kh(
    const unsigned short* __restrict__ slot,
    const bf16x8* __restrict__ bb,
    bf16x8 (&bcur)[4], f32x4 (&acc)[4][4], const int lane)
{
    #pragma unroll
    for (int kw = 0; kw < 3; ++kw) {
        #pragma unroll
        for (int kc = 0; kc < 4; ++kc) {
            const int g = KH * 12 + kw * 4 + kc;
            const int gn = (g == 35) ? 0 : g + 1;
            bf16x8 bnxt[4];
            #pragma unroll
            for (int j = 0; j < 4; ++j) bnxt[j] = bb[gn * 512 + j * 64];
            const int ka = kc * 32 + (lane >> 4) * 8;
            #pragma unroll
            for (int i = 0; i < 4; ++i) {
                const int m = i * 16 + (lane & 15) + kw;  // halo row in slot
                bf16x8 af = *(const bf16x8*)&slot[m * LDA + ka];
                #pragma unroll
                for (int j = 0; j < 4; ++j)
                    acc[i][j] = __builtin_amdgcn_mfma_f32_16x16x32_bf16(
                        af, bcur[j], acc[i][j], 0, 0, 0);
            }
            #pragma unroll
            for (int j = 0; j < 4; ++j) bcur[j] = bnxt[j];
        }
    }
}

// ---------------------------------------------------------------------------
// Conv kernel, rolling-row structure. Block = 64 px x 128 cout, 2 waves
// (wave = 64x64 via 4x4 MFMA). Each block owns a 16-row h-strip; 4-slot LDS
// ring holds input rows r-1..r+2 (slot(ri) = (ri-hs+1)&3). Per output row:
// one barrier; stage of input row r+2 is split T14-style (loads issued
// before a compute_kh, cvt+ds_write after) so HBM latency hides under MFMA.
// ---------------------------------------------------------------------------
__global__ __launch_bounds__(128) void conv_kernel(
    const float* __restrict__ x, const unsigned short* __restrict__ wprep,
    const float* __restrict__ noise_strength, const float* __restrict__ bias,
    const float* __restrict__ noise, float* __restrict__ out)
{
    __shared__ unsigned short ldsA[4 * SLOT];   // 71,808 B -> 2 blocks/CU
    const int tid  = threadIdx.x;
    const int lane = tid & 63;
    const int wn   = tid >> 6;        // wave: cout half (0..1)
    const int wt = blockIdx.x;        // 0..3 (w tile of 64)
    const int hs = blockIdx.y * 16;   // strip base output row
    const int b  = blockIdx.z;        // 0..7
    const int wstart = wt * 64;

    // ---- prologue: stage input rows hs-1, hs, hs+1 into slots 0,1,2 ----
    #pragma unroll 1
    for (int pr = 0; pr < 3; ++pr) {
        const int ri = hs + pr - 1;
        const bool rv = ((unsigned)ri < (unsigned)H);
        const float* rp = x + ((size_t)(b * H + ri) * W) * CIN;
        unsigned short* sl = &ldsA[pr * SLOT];
        #pragma unroll 1
        for (int idx = tid; idx < 66 * 32; idx += 128) {
            const int p  = idx >> 5;      // halo px 0..65 (w = wstart-1+p)
            const int c4 = idx & 31;
            const int wImg = wstart - 1 + p;
            float4 v = make_float4(0.f, 0.f, 0.f, 0.f);
            if (rv && (unsigned)wImg < (unsigned)W)
                v = *(const float4*)(rp + (size_t)wImg * CIN + c4 * 4);
            ushort4 u;
            u.x = f2bf(v.x); u.y = f2bf(v.y); u.z = f2bf(v.z); u.w = f2bf(v.w);
            *(ushort4*)&sl[p * LDA + c4 * 4] = u;
        }
    }

    // B pipeline: frag j of phase g at bb[g*512 + j*64]
    const bf16x8* bb = (const bf16x8*)wprep + wn * 256 + lane;
    bf16x8 bcur[4];
    #pragma unroll
    for (int j = 0; j < 4; ++j) bcur[j] = bb[j * 64];

    const float ns  = noise_strength[0] * 0.5f;
    const float RT2 = 1.41421356237309515f;
    float bfl[4];
    #pragma unroll
    for (int j = 0; j < 4; ++j) bfl[j] = bias[wn * 64 + j * 16 + (lane & 15)];

    f32x4 acc[4][4];

    #pragma unroll 1
    for (int r = 0; r < 16; ++r) {
        __syncthreads();   // all waves done with row r-1; slot (r+3)&3 free

        #pragma unroll
        for (int i = 0; i < 4; ++i)
            #pragma unroll
            for (int j = 0; j < 4; ++j)
                acc[i][j] = (f32x4){0.f, 0.f, 0.f, 0.f};

        const bool doStage = (r < 15);          // input row r+2 needed thru r=14
        const int riA = hs + r + 2;
        const bool rvA = ((unsigned)riA < (unsigned)H);
        const float* rpA = x + ((size_t)(b * H + riA) * W) * CIN;

        // -- stage chunk A: issue loads (idx 0..1151) --
        float4 stA[9];
        if (doStage) {
            #pragma unroll
            for (int k = 0; k < 9; ++k) {
                const int idx = tid + k * 128;
                const int p = idx >> 5, c4 = idx & 31;
                const int wImg = wstart - 1 + p;
                stA[k] = make_float4(0.f, 0.f, 0.f, 0.f);
                if (rvA && (unsigned)wImg < (unsigned)W)
                    stA[k] = *(const float4*)(rpA + (size_t)wImg * CIN + c4 * 4);
            }
        }

        compute_kh<0>(&ldsA[((r + 0) & 3) * SLOT], bb, bcur, acc, lane);

        unsigned short* sw = &ldsA[((r + 3) & 3) * SLOT];
        if (doStage) {   // chunk A cvt + LDS write (loads had kh0 to land)
            #pragma unroll
            for (int k = 0; k < 9; ++k) {
                const int idx = tid + k * 128;
                const int p = idx >> 5, c4 = idx & 31;
                ushort4 u;
                u.x = f2bf(stA[k].x); u.y = f2bf(stA[k].y);
                u.z = f2bf(stA[k].z); u.w = f2bf(stA[k].w);
                *(ushort4*)&sw[p * LDA + c4 * 4] = u;
            }
        }

        // -- stage chunk B: issue loads (idx 1152..2111) --
        float4 stB[8];
        if (doStage) {
            #pragma unroll
            for (int k = 0; k < 8; ++k) {
                const int idx = 1152 + tid + k * 128;
                const int p = idx >> 5, c4 = idx & 31;
                const int wImg = wstart - 1 + p;
                stB[k] = make_float4(0.f, 0.f, 0.f, 0.f);
                if (idx < 2112 && rvA && (unsigned)wImg < (unsigned)W)
                    stB[k] = *(const float4*)(rpA + (size_t)wImg * CIN + c4 * 4);
            }
        }

        compute_kh<1>(&ldsA[((r + 1) & 3) * SLOT], bb, bcur, acc, lane);

        if (doStage) {   // chunk B cvt + LDS write
            #pragma unroll
            for (int k = 0; k < 8; ++k) {
                const int idx = 1152 + tid + k * 128;
                if (idx < 2112) {
                    const int p = idx >> 5, c4 = idx & 31;
                    ushort4 u;
                    u.x = f2bf(stB[k].x); u.y = f2bf(stB[k].y);
                    u.z = f2bf(stB[k].z); u.w = f2bf(stB[k].w);
                    *(ushort4*)&sw[p * LDA + c4 * 4] = u;
                }
            }
        }

        // -- noise prefetch for this row (lands under kh2) --
        const int hrow = hs + r;
        const size_t pixBase = ((size_t)(b * H + hrow) * W) + wstart;
        float nz[4][4];
        #pragma unroll
        for (int i = 0; i < 4; ++i)
            #pragma unroll
            for (int rr = 0; rr < 4; ++rr)
                nz[i][rr] = noise[pixBase + i * 16 + ((lane >> 4) << 2) + rr] * ns;

        compute_kh<2>(&ldsA[((r + 2) & 3) * SLOT], bb, bcur, acc, lane);

        // ---- epilogue row r: noise + bias + lrelu(0.2)*sqrt(2) ----
        #pragma unroll
        for (int i = 0; i < 4; ++i) {
            const int mbase = i * 16 + ((lane >> 4) << 2);
            #pragma unroll
            for (int rr = 0; rr < 4; ++rr) {
                const size_t pix = pixBase + (mbase + rr);
                #pragma unroll
                for (int j = 0; j < 4; ++j) {
                    const int col = wn * 64 + j * 16 + (lane & 15);
                    float v = acc[i][j][rr] + nz[i][rr] + bfl[j];
                    v = (v >= 0.f ? v : 0.2f * v) * RT2;
                    out[pix * COUT + col] = v;
                }
            }
        }
    }
}

extern "C" void kernel_launch(void* const* d_in, const int* in_sizes, int n_in,
                              void* d_out, int out_size, void* d_ws, size_t ws_size,
                              hipStream_t stream) {
    const float* x              = (const float*)d_in[0];
    const float* style          = (const float*)d_in[1];
    const float* kern           = (const float*)d_in[2];
    const float* w_mod          = (const float*)d_in[3];
    const float* b_mod          = (const float*)d_in[4];
    const float* noise_strength = (const float*)d_in[5];
    const float* bias           = (const float*)d_in[6];
    const float* noise          = (const float*)d_in[7];
    float* out = (float*)d_out;
    unsigned short* wprep = (unsigned short*)d_ws;  // 294,912 B of scratch

    hipLaunchKernelGGL(mod_style, dim3(8), dim3(256), 0, stream,
                       style, w_mod, b_mod);
    hipLaunchKernelGGL(demod_partial, dim3(9), dim3(256), 0, stream, kern);
    hipLaunchKernelGGL(swizzle_kernel, dim3(72), dim3(256), 0, stream,
                       kern, wprep);
    hipLaunchKernelGGL(conv_kernel, dim3(4, 16, 8), dim3(128), 0, stream,
                       x, wprep, noise_strength, bias, noise, out);
}

// Round 4
// 625.814 us; speedup vs baseline: 1.3878x; 1.3878x over previous
//
#include <hip/hip_runtime.h>
#include <hip/hip_bf16.h>

#define H 256
#define W 256
#define CIN 128
#define COUT 128
#define BATCH 8
#define LDA 136  // LDS row stride in bf16 elements (128 + 8 pad, keeps 16B align)

typedef float f32x4 __attribute__((ext_vector_type(4)));
typedef short bf16x8 __attribute__((ext_vector_type(8)));

static __device__ __forceinline__ unsigned short f2bf(float f) {
    unsigned int x = __float_as_uint(f);
    unsigned int r = (x + 0x7fffu + ((x >> 16) & 1u)) >> 16;
    return (unsigned short)r;
}

// Cross-kernel scratch (stream-ordered kernel launches provide visibility).
__device__ float g_s0[CIN];        // s[0][c] (un-normalized)
__device__ float g_bmax[BATCH];    // per-batch max |s[b][c]|
__device__ float g_partial[9 * COUT];  // per-kk partial sum of (w*scale)^2

// ---------------------------------------------------------------------------
// Prep stage 1: s = style @ w_mod + b_mod + 1. One block per batch image.
// ---------------------------------------------------------------------------
__global__ __launch_bounds__(256) void mod_style(
    const float* __restrict__ style, const float* __restrict__ w_mod,
    const float* __restrict__ b_mod)
{
    __shared__ float red[256];
    const int t = threadIdx.x;
    const int b = blockIdx.x;
    const int c = t & 127;
    const int half = t >> 7;

    float acc = 0.f;
    const float4* st4 = (const float4*)(style + b * 512 + half * 256);
    const float* wm = w_mod + half * 256 * CIN + c;
    for (int k4 = 0; k4 < 64; ++k4) {
        float4 s4 = st4[k4];
        const float* w = wm + k4 * 4 * CIN;
        acc += s4.x * w[0 * CIN];
        acc += s4.y * w[1 * CIN];
        acc += s4.z * w[2 * CIN];
        acc += s4.w * w[3 * CIN];
    }
    red[t] = acc;
    __syncthreads();
    if (t < 128) {
        float sval = red[t] + red[t + 128] + b_mod[t] + 1.0f;
        if (b == 0) g_s0[t] = sval;
        red[t] = fabsf(sval);
    }
    __syncthreads();
    for (int off = 64; off > 0; off >>= 1) {
        if (t < off) red[t] = fmaxf(red[t], red[t + off]);
        __syncthreads();
    }
    if (t == 0) g_bmax[b] = red[0];
}

// ---------------------------------------------------------------------------
// Prep stage 2: partial demod sums. One block per kk (9 blocks, 256 threads).
// ---------------------------------------------------------------------------
__global__ __launch_bounds__(256) void demod_partial(
    const float* __restrict__ kern)
{
    __shared__ float scale[CIN];
    __shared__ float red[256];
    const int t = threadIdx.x;
    const int kk = blockIdx.x;
    const int co = t & 127;
    const int half = t >> 7;

    if (t < 128) {
        float m = g_bmax[0];
        #pragma unroll
        for (int i = 1; i < BATCH; ++i) m = fmaxf(m, g_bmax[i]);
        const float he_std = 1.0f / sqrtf(1152.0f);
        scale[t] = g_s0[t] * (1.0f / m) * he_std;
    }
    __syncthreads();

    float ss = 0.f;
    const float* kbase = kern + (size_t)kk * 128 * 128 + co;
    for (int j = 0; j < 64; ++j) {
        int ci = half * 64 + j;
        float wv = kbase[(size_t)ci * 128] * scale[ci];
        ss += wv * wv;
    }
    red[t] = ss;
    __syncthreads();
    if (t < 128) g_partial[kk * 128 + t] = red[t] + red[t + 128];
}

// ---------------------------------------------------------------------------
// Prep stage 3: write pre-swizzled bf16 B-fragments (one unit per thread).
// Unit u = ((kk*4 + kc)*8 + ntile)*64 + lane; each unit 8 bf16 =
// B[k = kc*32 + (lane>>4)*8 + j][n = ntile*16 + (lane&15)], kk = kh*3+kw.
// ---------------------------------------------------------------------------
__global__ __launch_bounds__(256) void swizzle_kernel(
    const float* __restrict__ kern, unsigned short* __restrict__ wprep)
{
    __shared__ float scale[CIN];
    __shared__ float dArr[COUT];
    const int t = threadIdx.x;
    const int u = blockIdx.x * 256 + t;

    if (t < 128) {
        float m = g_bmax[0];
        #pragma unroll
        for (int i = 1; i < BATCH; ++i) m = fmaxf(m, g_bmax[i]);
        const float he_std = 1.0f / sqrtf(1152.0f);
        scale[t] = g_s0[t] * (1.0f / m) * he_std;
        float sum = 0.f;
        #pragma unroll
        for (int g = 0; g < 9; ++g) sum += g_partial[g * 128 + t];
        dArr[t] = rsqrtf(sum + 1e-8f);
    }
    __syncthreads();

    const int lane  = u & 63;
    const int ntile = (u >> 6) & 7;
    const int kc    = (u >> 9) & 3;
    const int kk    = u >> 11;
    const int co  = ntile * 16 + (lane & 15);
    const int cib = kc * 32 + (lane >> 4) * 8;
    const float dv = dArr[co];
    unsigned int packed[4];
    #pragma unroll
    for (int jp = 0; jp < 4; ++jp) {
        int ci0 = cib + jp * 2;
        float w0 = kern[(kk * 128 + ci0)     * 128 + co] * scale[ci0]     * dv;
        float w1 = kern[(kk * 128 + ci0 + 1) * 128 + co] * scale[ci0 + 1] * dv;
        packed[jp] = (unsigned int)f2bf(w0) | ((unsigned int)f2bf(w1) << 16);
    }
    ((uint4*)wprep)[u] = make_uint4(packed[0], packed[1], packed[2], packed[3]);
}

// ---------------------------------------------------------------------------
// Staging helpers: one input halo row (130 px x 128 cin) per LDS buffer.
// issue_row: 17 float4 global loads/thread into regs (no wait here).
// write_row: cvt fp32->bf16 + ds_write (compiler inserts counted vmcnt).
// ---------------------------------------------------------------------------
static __device__ __forceinline__ void issue_row(
    float4 (&st)[17], const float* __restrict__ x, int b, int hImg,
    int wstart, int tid)
{
    const bool rv = ((unsigned)hImg < (unsigned)H);
    const float* rp = x + ((size_t)(b * H + hImg) * W) * CIN;
    #pragma unroll
    for (int k = 0; k < 17; ++k) {
        const int idx = tid + k * 256;          // 0..4159 (130 px * 32 f4)
        st[k] = make_float4(0.f, 0.f, 0.f, 0.f);
        if (k < 16 || tid < 64) {
            const int p  = idx >> 5;            // halo px 0..129
            const int c4 = idx & 31;
            const int wImg = wstart - 1 + p;
            if (rv && (unsigned)wImg < (unsigned)W)
                st[k] = *(const float4*)(rp + (size_t)wImg * CIN + c4 * 4);
        }
    }
}

static __device__ __forceinline__ void write_row(
    const float4 (&st)[17], unsigned short* __restrict__ buf, int tid)
{
    #pragma unroll
    for (int k = 0; k < 17; ++k) {
        const int idx = tid + k * 256;
        if (k < 16 || tid < 64) {
            const int p  = idx >> 5;
            const int c4 = idx & 31;
            ushort4 u;
            u.x = f2bf(st[k].x); u.y = f2bf(st[k].y);
            u.z = f2bf(st[k].z); u.w = f2bf(st[k].w);
            *(ushort4*)&buf[p * LDA + c4 * 4] = u;
        }
    }
}

// ---------------------------------------------------------------------------
// 12 MFMA phases for one kh. B-fragments flow through a 2-deep register
// pipeline bp[2][4]: phase p consumes bp[p&1] and reloads that set with
// phase p+2's fragments right after the last MFMA using it. The consuming
// wait therefore lands on loads issued ~2 phases earlier (counted vmcnt,
// no FIFO drain of staging loads).
// ---------------------------------------------------------------------------
template<int KH>
static __device__ __forceinline__ void compute_kh(
    const unsigned short* __restrict__ slot,
    const bf16x8* __restrict__ bb,
    bf16x8 (&bp)[2][4], f32x4 (&acc)[4][4], const int lane, const int wm)
{
    #pragma unroll
    for (int kw = 0; kw < 3; ++kw) {
        #pragma unroll
        for (int kc = 0; kc < 4; ++kc) {
            const int p   = KH * 12 + kw * 4 + kc;   // compile-time 0..35
            const int sel = p & 1;
            const int ka  = kc * 32 + (lane >> 4) * 8;
            #pragma unroll
            for (int i = 0; i < 4; ++i) {
                const int m = wm * 64 + i * 16 + (lane & 15) + kw;  // halo row
                bf16x8 af = *(const bf16x8*)&slot[m * LDA + ka];
                #pragma unroll
                for (int j = 0; j < 4; ++j)
                    acc[i][j] = __builtin_amdgcn_mfma_f32_16x16x32_bf16(
                        af, bp[sel][j], acc[i][j], 0, 0, 0);
            }
            const int gn = (p + 2 < 36) ? p + 2 : p + 2 - 36;  // wrap harmless
            #pragma unroll
            for (int j = 0; j < 4; ++j) bp[sel][j] = bb[gn * 512 + j * 64];
        }
    }
}

// ---------------------------------------------------------------------------
// Conv kernel (round-2 shape + pipelining). Block = 128 px x 128 cout,
// 4 waves 2x2, wave = 64x64 via 4x4 mfma_f32_16x16x32_bf16.
// Double-buffered LDS row staging: loads for row kh+1 issued at the TAIL of
// kh-1 (before the barrier), cvt+ds_write after kh's phases -> HBM latency
// hides under 12 MFMA phases; every vmcnt is counted, none drains to 0.
// LDS 70.7 KB -> 2 blocks/CU (8 waves/CU). VGPR budget ~195 (<256, 2/SIMD).
// ---------------------------------------------------------------------------
__global__ __launch_bounds__(256, 2) void conv_kernel(
    const float* __restrict__ x, const unsigned short* __restrict__ wprep,
    const float* __restrict__ noise_strength, const float* __restrict__ bias,
    const float* __restrict__ noise, float* __restrict__ out)
{
    __shared__ unsigned short ldsA[2][130 * LDA];   // 2 x 35,360 B
    const int tid  = threadIdx.x;
    const int lane = tid & 63;
    const int wave = tid >> 6;
    const int wm = wave & 1;   // wave row (pixels)
    const int wn = wave >> 1;  // wave col (couts)
    const int wt = blockIdx.x;        // 0..1 (w tile)
    const int h  = blockIdx.y;        // 0..255
    const int b  = blockIdx.z;        // 0..7
    const int wstart = wt * 128;

    f32x4 acc[4][4];
    #pragma unroll
    for (int i = 0; i < 4; ++i)
        #pragma unroll
        for (int j = 0; j < 4; ++j) acc[i][j] = (f32x4){0.f, 0.f, 0.f, 0.f};

    // B pipeline: frag j of phase g at bb[g*512 + j*64]; preload phases 0,1.
    const bf16x8* bb = (const bf16x8*)wprep + wn * 256 + lane;
    bf16x8 bp[2][4];
    #pragma unroll
    for (int j = 0; j < 4; ++j) bp[0][j] = bb[j * 64];
    #pragma unroll
    for (int j = 0; j < 4; ++j) bp[1][j] = bb[512 + j * 64];

    float4 st[17];

    // ---- prologue: row h-1 -> buf0 (serial); issue row h; barrier ----
    issue_row(st, x, b, h - 1, wstart, tid);
    write_row(st, ldsA[0], tid);
    issue_row(st, x, b, h, wstart, tid);
    __syncthreads();

    // ---- kh = 0: compute buf0; cvt row h -> buf1; issue row h+1 ----
    compute_kh<0>(ldsA[0], bb, bp, acc, lane, wm);
    write_row(st, ldsA[1], tid);
    issue_row(st, x, b, h + 1, wstart, tid);
    __syncthreads();

    // ---- kh = 1: compute buf1; cvt row h+1 -> buf0 ----
    compute_kh<1>(ldsA[1], bb, bp, acc, lane, wm);
    write_row(st, ldsA[0], tid);
    __syncthreads();

    // ---- kh = 2: compute buf0 ----
    compute_kh<2>(ldsA[0], bb, bp, acc, lane, wm);

    // ---- epilogue: noise + bias + lrelu(0.2)*sqrt(2) ----
    const float ns  = noise_strength[0] * 0.5f;
    const float RT2 = 1.41421356237309515f;
    const size_t pixBase = ((size_t)(b * H + h) * W) + wstart;
    #pragma unroll
    for (int i = 0; i < 4; ++i) {
        const int mbase = wm * 64 + i * 16 + ((lane >> 4) << 2);
        #pragma unroll
        for (int r = 0; r < 4; ++r) {
            const size_t pix = pixBase + (mbase + r);
            const float nz = noise[pix] * ns;
            #pragma unroll
            for (int j = 0; j < 4; ++j) {
                const int col = wn * 64 + j * 16 + (lane & 15);
                float v = acc[i][j][r] + nz + bias[col];
                v = (v >= 0.f ? v : 0.2f * v) * RT2;
                out[pix * COUT + col] = v;
            }
        }
    }
}

extern "C" void kernel_launch(void* const* d_in, const int* in_sizes, int n_in,
                              void* d_out, int out_size, void* d_ws, size_t ws_size,
                              hipStream_t stream) {
    const float* x              = (const float*)d_in[0];
    const float* style          = (const float*)d_in[1];
    const float* kern           = (const float*)d_in[2];
    const float* w_mod          = (const float*)d_in[3];
    const float* b_mod          = (const float*)d_in[4];
    const float* noise_strength = (const float*)d_in[5];
    const float* bias           = (const float*)d_in[6];
    const float* noise          = (const float*)d_in[7];
    float* out = (float*)d_out;
    unsigned short* wprep = (unsigned short*)d_ws;  // 294,912 B of scratch

    hipLaunchKernelGGL(mod_style, dim3(8), dim3(256), 0, stream,
                       style, w_mod, b_mod);
    hipLaunchKernelGGL(demod_partial, dim3(9), dim3(256), 0, stream, kern);
    hipLaunchKernelGGL(swizzle_kernel, dim3(72), dim3(256), 0, stream,
                       kern, wprep);
    hipLaunchKernelGGL(conv_kernel, dim3(2, 256, 8), dim3(256), 0, stream,
                       x, wprep, noise_strength, bias, noise, out);
}